// Round 16
// baseline (353.043 us; speedup 1.0000x reference)
//
#include <hip/hip_runtime.h>
#include <math.h>

#define S 128
#define R 384
#define CM 256
#define CZ 128
#define H 8
#define D 32
#define INFB 1e9f
#define LN_EPS 1e-5f
#define LOG2E 1.4426950408889634f

typedef unsigned short u16;
typedef short bf16x8 __attribute__((ext_vector_type(8)));
typedef short bf16x4 __attribute__((ext_vector_type(4)));
typedef float f32x4 __attribute__((ext_vector_type(4)));

#define NRTOT ((size_t)S * R)   // 49152 rows

__device__ inline float wave_reduce_sum(float v) {
    #pragma unroll
    for (int o = 32; o > 0; o >>= 1) v += __shfl_xor(v, o, 64);
    return v;
}

__device__ inline u16 f2bf(float f) {
    union { float f; unsigned int u; } x; x.f = f;
    unsigned int r = x.u + 0x7fffu + ((x.u >> 16) & 1u);
    return (u16)(r >> 16);
}

__device__ inline float bf2f(u16 v) {
    union { unsigned int u; float f; } x; x.u = ((unsigned int)v) << 16;
    return x.f;
}

// ---------------------------------------------------------------------------
// Weight prep: Wt[mi][n][k] = src_mi[k][n] as bf16; mi: 0=q(scaled),1=k,2=v,3=g,4=o
__global__ __launch_bounds__(256) void wprep_kernel(
    const float* __restrict__ wq, const float* __restrict__ wk,
    const float* __restrict__ wv, const float* __restrict__ wg,
    const float* __restrict__ wo, u16* __restrict__ Wt) {
    int n = blockIdx.x & 255;
    int mi = blockIdx.x >> 8;
    int kc = threadIdx.x;
    const float* src = mi == 0 ? wq : mi == 1 ? wk : mi == 2 ? wv
                     : mi == 3 ? wg : wo;
    float val = src[(size_t)kc * 256 + n];
    if (mi == 0) val *= 0.17677669529663687f * LOG2E;
    Wt[((size_t)mi * 256 + n) * 256 + kc] = f2bf(val);
}

// ---------------------------------------------------------------------------
// LN(m) -> A bf16 [S*R][256]. 4 rows per block, wave per row.
__global__ __launch_bounds__(256) void lnm_kernel(
    const float* __restrict__ m, const float* __restrict__ lnw,
    const float* __restrict__ lnb, u16* __restrict__ A) {
    int t = threadIdx.x;
    int wave = t >> 6, lane = t & 63;
    size_t row = (size_t)blockIdx.x * 4 + wave;
    float4 x = ((const float4*)(m + row * 256))[lane];
    float ss = wave_reduce_sum(x.x + x.y + x.z + x.w);
    float sq = wave_reduce_sum(x.x * x.x + x.y * x.y + x.z * x.z + x.w * x.w);
    float mu = ss * (1.0f / 256.0f);
    float var = sq * (1.0f / 256.0f) - mu * mu;
    float rstd = rsqrtf(var + LN_EPS);
    int c = lane * 4;
    ushort4 o4;
    o4.x = f2bf((x.x - mu) * rstd * lnw[c]     + lnb[c]);
    o4.y = f2bf((x.y - mu) * rstd * lnw[c + 1] + lnb[c + 1]);
    o4.z = f2bf((x.z - mu) * rstd * lnw[c + 2] + lnb[c + 2]);
    o4.w = f2bf((x.w - mu) * rstd * lnw[c + 3] + lnb[c + 3]);
    ((ushort4*)(A + row * 256))[lane] = o4;
}

// ---------------------------------------------------------------------------
// z_bias: algebra-folded, 16 lanes per (i,j) pair, 4 pairs per wave.
// Natural layout [h][i=qrow][j=key], coalesced writes. Pre-scaled by LOG2E.
__global__ __launch_bounds__(256) void zbias_kernel(
    const float* __restrict__ z, const float* __restrict__ lnw,
    const float* __restrict__ lnb, const float* __restrict__ wz,
    float* __restrict__ zbias) {
    int t = threadIdx.x;
    int lane = t & 63, wave = t >> 6;
    int g = lane >> 4, u = lane & 15;
    int c0 = u * 8;

    float lw[8], lb[8];
    {
        float4 a = *(const float4*)(lnw + c0);
        float4 b = *(const float4*)(lnw + c0 + 4);
        lw[0]=a.x; lw[1]=a.y; lw[2]=a.z; lw[3]=a.w;
        lw[4]=b.x; lw[5]=b.y; lw[6]=b.z; lw[7]=b.w;
        float4 c = *(const float4*)(lnb + c0);
        float4 d = *(const float4*)(lnb + c0 + 4);
        lb[0]=c.x; lb[1]=c.y; lb[2]=c.z; lb[3]=c.w;
        lb[4]=d.x; lb[5]=d.y; lb[6]=d.z; lb[7]=d.w;
        #pragma unroll
        for (int i = 0; i < 8; ++i) { lw[i] *= LOG2E; lb[i] *= LOG2E; }
    }
    float uw[8][8];
    float bwp[8];
    #pragma unroll
    for (int h = 0; h < 8; ++h) bwp[h] = 0.f;
    #pragma unroll
    for (int i = 0; i < 8; ++i) {
        float4 w0 = *(const float4*)(wz + (size_t)(c0 + i) * 8);
        float4 w1 = *(const float4*)(wz + (size_t)(c0 + i) * 8 + 4);
        uw[i][0] = lw[i] * w0.x; uw[i][1] = lw[i] * w0.y;
        uw[i][2] = lw[i] * w0.z; uw[i][3] = lw[i] * w0.w;
        uw[i][4] = lw[i] * w1.x; uw[i][5] = lw[i] * w1.y;
        uw[i][6] = lw[i] * w1.z; uw[i][7] = lw[i] * w1.w;
        bwp[0] = fmaf(lb[i], w0.x, bwp[0]); bwp[1] = fmaf(lb[i], w0.y, bwp[1]);
        bwp[2] = fmaf(lb[i], w0.z, bwp[2]); bwp[3] = fmaf(lb[i], w0.w, bwp[3]);
        bwp[4] = fmaf(lb[i], w1.x, bwp[4]); bwp[5] = fmaf(lb[i], w1.y, bwp[5]);
        bwp[6] = fmaf(lb[i], w1.z, bwp[6]); bwp[7] = fmaf(lb[i], w1.w, bwp[7]);
    }

    const int nwaves = gridDim.x * 4;
    int wid = blockIdx.x * 4 + wave;
    #pragma unroll 1
    for (int it = 0; it < 4; ++it) {
        int p = (wid + it * nwaves) * 4 + g;
        const float* zp = z + (size_t)p * CZ + c0;
        float4 z0 = *(const float4*)zp;
        float4 z1 = *(const float4*)(zp + 4);
        float x[8] = {z0.x, z0.y, z0.z, z0.w, z1.x, z1.y, z1.z, z1.w};
        float ss = 0.f, sq = 0.f;
        #pragma unroll
        for (int i = 0; i < 8; ++i) { ss += x[i]; sq = fmaf(x[i], x[i], sq); }
        #pragma unroll
        for (int o = 1; o < 16; o <<= 1) {
            ss += __shfl_xor(ss, o, 64);
            sq += __shfl_xor(sq, o, 64);
        }
        float mu = ss * (1.0f / CZ);
        float var = sq * (1.0f / CZ) - mu * mu;
        float rstd = rsqrtf(var + LN_EPS);
        float ph[8];
        #pragma unroll
        for (int h = 0; h < 8; ++h) ph[h] = bwp[h];
        #pragma unroll
        for (int i = 0; i < 8; ++i) {
            float ti = (x[i] - mu) * rstd;
            #pragma unroll
            for (int h = 0; h < 8; ++h) ph[h] = fmaf(ti, uw[i][h], ph[h]);
        }
        #pragma unroll
        for (int h = 0; h < 8; ++h) {
            #pragma unroll
            for (int o = 1; o < 16; o <<= 1) ph[h] += __shfl_xor(ph[h], o, 64);
        }
        if (u < 8) {
            float outv = ph[0];
            if (u == 1) outv = ph[1];
            if (u == 2) outv = ph[2];
            if (u == 3) outv = ph[3];
            if (u == 4) outv = ph[4];
            if (u == 5) outv = ph[5];
            if (u == 6) outv = ph[6];
            if (u == 7) outv = ph[7];
            zbias[(size_t)u * (R * R) + p] = outv;  // [h][i][j], coalesced
        }
    }
}

// ---------------------------------------------------------------------------
// qkvg GEMM: M=49152, K=256, one weight matrix per blockIdx.y.
// HEAD-MAJOR outputs: q,k,g stored as [h][S*R][32]; v TRANSPOSED+SLOT-PERMUTED.
__global__ __launch_bounds__(512) void qkvg_gemm(
    const u16* __restrict__ A, const u16* __restrict__ Wt,
    const float* __restrict__ bg,
    u16* __restrict__ q, u16* __restrict__ k, u16* __restrict__ vT,
    u16* __restrict__ g) {
    int nb = blockIdx.y;
    size_t row0 = (size_t)blockIdx.x * 128;
    int t = threadIdx.x, lane = t & 63, wave = t >> 6;
    int l15 = lane & 15, l4 = lane >> 4;
    int wm = (wave >> 2) * 64, wn = (wave & 3) * 64;
    const u16* B = Wt + (size_t)nb * 256 * 256;
    const u16* Ab = A + (row0 + wm + l15) * 256 + l4 * 8;
    const u16* Bb = B + (size_t)(wn + l15) * 256 + l4 * 8;

    f32x4 acc[4][4];
    #pragma unroll
    for (int mt = 0; mt < 4; ++mt)
        #pragma unroll
        for (int nt = 0; nt < 4; ++nt)
            acc[mt][nt] = (f32x4){0.f, 0.f, 0.f, 0.f};

    #pragma unroll
    for (int kk = 0; kk < 8; ++kk) {
        bf16x8 af[4], bfr[4];
        #pragma unroll
        for (int mt = 0; mt < 4; ++mt)
            af[mt] = *(const bf16x8*)(Ab + (size_t)mt * 16 * 256 + kk * 32);
        #pragma unroll
        for (int nt = 0; nt < 4; ++nt)
            bfr[nt] = *(const bf16x8*)(Bb + (size_t)nt * 16 * 256 + kk * 32);
        #pragma unroll
        for (int mt = 0; mt < 4; ++mt)
            #pragma unroll
            for (int nt = 0; nt < 4; ++nt)
                acc[mt][nt] = __builtin_amdgcn_mfma_f32_16x16x32_bf16(
                    af[mt], bfr[nt], acc[mt][nt], 0, 0, 0);
    }

    if (nb == 3) {
        #pragma unroll
        for (int nt = 0; nt < 4; ++nt) {
            int col = wn + nt * 16 + l15;
            int hh = col >> 5, dd = col & 31;
            float bgv = bg[col];
            #pragma unroll
            for (int mt = 0; mt < 4; ++mt)
                #pragma unroll
                for (int r = 0; r < 4; ++r) {
                    size_t row = row0 + wm + mt * 16 + l4 * 4 + r;
                    g[((size_t)hh * NRTOT + row) * 32 + dd] =
                        f2bf(1.0f / (1.0f + __expf(-(acc[mt][nt][r] + bgv))));
                }
        }
    } else if (nb == 2) {
        #pragma unroll
        for (int nt = 0; nt < 4; ++nt) {
            int col = wn + nt * 16 + l15;
            int hh = col >> 5, dd = col & 31;
            #pragma unroll
            for (int mt = 0; mt < 4; ++mt) {
                size_t row = row0 + wm + mt * 16 + l4 * 4;  // 4-aligned
                int ss = (int)(row / 384);
                int rr = (int)(row - (size_t)ss * 384);
                int blk = rr & ~31;
                int k5 = rr & 31;
                int poff = blk + ((k5 & 15) >> 2) * 8 + ((k5 & 16) ? 4 : 0);
                ushort4 pk;
                pk.x = f2bf(acc[mt][nt][0]);
                pk.y = f2bf(acc[mt][nt][1]);
                pk.z = f2bf(acc[mt][nt][2]);
                pk.w = f2bf(acc[mt][nt][3]);
                *(ushort4*)(vT + ((size_t)(ss * 8 + hh) * 32 + dd) * 384 + poff) = pk;
            }
        }
    } else {
        u16* dst = nb == 0 ? q : k;
        #pragma unroll
        for (int nt = 0; nt < 4; ++nt) {
            int col = wn + nt * 16 + l15;
            int hh = col >> 5, dd = col & 31;
            #pragma unroll
            for (int mt = 0; mt < 4; ++mt)
                #pragma unroll
                for (int r = 0; r < 4; ++r) {
                    size_t row = row0 + wm + mt * 16 + l4 * 4 + r;
                    dst[((size_t)hh * NRTOT + row) * 32 + dd] = f2bf(acc[mt][nt][r]);
                }
        }
    }
}

// ---------------------------------------------------------------------------
// out GEMM: M=49152, N=256, K=256; A = o in HEAD-MAJOR [h][S*R][32].
__global__ __launch_bounds__(512) void out_gemm(
    const u16* __restrict__ A, const u16* __restrict__ Wt,
    const float* __restrict__ bo, float* __restrict__ out) {
    size_t row0 = (size_t)blockIdx.x * 128;
    int t = threadIdx.x, lane = t & 63, wave = t >> 6;
    int l15 = lane & 15, l4 = lane >> 4;
    int wm = (wave >> 2) * 64, wn = (wave & 3) * 64;
    const u16* Bb = Wt + (size_t)(wn + l15) * 256 + l4 * 8;

    f32x4 acc[4][4];
    #pragma unroll
    for (int mt = 0; mt < 4; ++mt)
        #pragma unroll
        for (int nt = 0; nt < 4; ++nt)
            acc[mt][nt] = (f32x4){0.f, 0.f, 0.f, 0.f};

    #pragma unroll
    for (int kk = 0; kk < 8; ++kk) {
        bf16x8 af[4], bfr[4];
        #pragma unroll
        for (int mt = 0; mt < 4; ++mt)
            af[mt] = *(const bf16x8*)(A +
                ((size_t)kk * NRTOT + row0 + wm + mt * 16 + l15) * 32 + l4 * 8);
        #pragma unroll
        for (int nt = 0; nt < 4; ++nt)
            bfr[nt] = *(const bf16x8*)(Bb + (size_t)nt * 16 * 256 + kk * 32);
        #pragma unroll
        for (int mt = 0; mt < 4; ++mt)
            #pragma unroll
            for (int nt = 0; nt < 4; ++nt)
                acc[mt][nt] = __builtin_amdgcn_mfma_f32_16x16x32_bf16(
                    af[mt], bfr[nt], acc[mt][nt], 0, 0, 0);
    }

    #pragma unroll
    for (int nt = 0; nt < 4; ++nt) {
        int col = wn + nt * 16 + l15;
        float bov = bo[col];
        #pragma unroll
        for (int mt = 0; mt < 4; ++mt)
            #pragma unroll
            for (int r = 0; r < 4; ++r) {
                size_t row = row0 + wm + mt * 16 + l4 * 4 + r;
                out[row * 256 + col] = acc[mt][nt][r] + bov;
            }
    }
}

// ---------------------------------------------------------------------------
// Attention v11: v10 + explicit depth-1 software pipeline (Tile struct,
// fully unrolled loop, next-tile loads issued before current compute) and
// mask+zbias bias folded at load time (critical path = add + exp2 only).
struct Tile {
    bf16x8 kf0, kf1, vb0, vb1;
    f32x4 bz0[2], bz1[2];   // (mask-1)*MSC + zb, per rt, per key-half
};

__device__ inline Tile load_tile(const u16* kh, const u16* vbase,
                                 const float* zbh, const float* mrow,
                                 int wq0, int l15, int l4, int kt) {
    const float MSC = INFB * LOG2E;
    Tile tl;
    tl.kf0 = *(const bf16x8*)(kh + (size_t)(kt + l15) * 32 + l4 * 8);
    tl.kf1 = *(const bf16x8*)(kh + (size_t)(kt + 16 + l15) * 32 + l4 * 8);
    tl.vb0 = *(const bf16x8*)(vbase + (size_t)l15 * 384 + kt + l4 * 8);
    tl.vb1 = *(const bf16x8*)(vbase + (size_t)(16 + l15) * 384 + kt + l4 * 8);
    float4 mk0 = *(const float4*)(mrow + kt + l4 * 4);
    float4 mk1 = *(const float4*)(mrow + kt + 16 + l4 * 4);
    f32x4 mv0, mv1;
    mv0[0] = (mk0.x - 1.0f) * MSC; mv0[1] = (mk0.y - 1.0f) * MSC;
    mv0[2] = (mk0.z - 1.0f) * MSC; mv0[3] = (mk0.w - 1.0f) * MSC;
    mv1[0] = (mk1.x - 1.0f) * MSC; mv1[1] = (mk1.y - 1.0f) * MSC;
    mv1[2] = (mk1.z - 1.0f) * MSC; mv1[3] = (mk1.w - 1.0f) * MSC;
    #pragma unroll
    for (int rt = 0; rt < 2; ++rt) {
        const float* zq = zbh + (size_t)(wq0 + rt * 16 + l15) * R;
        f32x4 zv0 = *(const f32x4*)(zq + kt + l4 * 4);
        f32x4 zv1 = *(const f32x4*)(zq + kt + 16 + l4 * 4);
        tl.bz0[rt] = zv0 + mv0;
        tl.bz1[rt] = zv1 + mv1;
    }
    return tl;
}

__device__ inline void compute_tile(const Tile& tl, const bf16x8* qf,
                                    f32x4 (*oacc)[2], float* pden) {
    const f32x4 z4 = {0.f, 0.f, 0.f, 0.f};
    #pragma unroll
    for (int rt = 0; rt < 2; ++rt) {
        f32x4 sf0 = __builtin_amdgcn_mfma_f32_16x16x32_bf16(tl.kf0, qf[rt], z4, 0, 0, 0);
        f32x4 sf1 = __builtin_amdgcn_mfma_f32_16x16x32_bf16(tl.kf1, qf[rt], z4, 0, 0, 0);
        float e0 = exp2f(sf0[0] + tl.bz0[rt][0]);
        float e1 = exp2f(sf0[1] + tl.bz0[rt][1]);
        float e2 = exp2f(sf0[2] + tl.bz0[rt][2]);
        float e3 = exp2f(sf0[3] + tl.bz0[rt][3]);
        float e4 = exp2f(sf1[0] + tl.bz1[rt][0]);
        float e5 = exp2f(sf1[1] + tl.bz1[rt][1]);
        float e6 = exp2f(sf1[2] + tl.bz1[rt][2]);
        float e7 = exp2f(sf1[3] + tl.bz1[rt][3]);
        pden[rt] += ((e0 + e1) + (e2 + e3)) + ((e4 + e5) + (e6 + e7));
        bf16x8 pa;
        pa[0] = (short)f2bf(e0); pa[1] = (short)f2bf(e1);
        pa[2] = (short)f2bf(e2); pa[3] = (short)f2bf(e3);
        pa[4] = (short)f2bf(e4); pa[5] = (short)f2bf(e5);
        pa[6] = (short)f2bf(e6); pa[7] = (short)f2bf(e7);
        oacc[rt][0] = __builtin_amdgcn_mfma_f32_16x16x32_bf16(
            pa, tl.vb0, oacc[rt][0], 0, 0, 0);
        oacc[rt][1] = __builtin_amdgcn_mfma_f32_16x16x32_bf16(
            pa, tl.vb1, oacc[rt][1], 0, 0, 0);
    }
}

__global__ __launch_bounds__(768) void attn_kernel(
    const u16* __restrict__ q, const u16* __restrict__ k,
    const u16* __restrict__ vT, const u16* __restrict__ g,
    const float* __restrict__ mask, const float* __restrict__ zb,
    u16* __restrict__ o) {
    int h = blockIdx.x, s = blockIdx.y;
    int t = threadIdx.x;
    int lane = t & 63, wave = t >> 6;   // wave in [0,12)
    int l15 = lane & 15, l4 = lane >> 4;

    size_t hbase = ((size_t)h * NRTOT + (size_t)s * R) * 32;
    const u16* qh = q + hbase;
    const u16* kh = k + hbase;
    const u16* gh = g + hbase;
    u16* oh = o + hbase;
    const u16* vbase = vT + ((size_t)(s * H + h) * 32) * 384;
    const float* zbh = zb + (size_t)h * R * R;   // [qrow][key]
    const float* mrow = mask + (size_t)s * R;

    int wq0 = wave * 32;
    bf16x8 qf[2];     // B-operand: col = qrow (l15), k-elems l4*8..
    #pragma unroll
    for (int rt = 0; rt < 2; ++rt)
        qf[rt] = *(const bf16x8*)(qh + (size_t)(wq0 + rt * 16 + l15) * 32 + l4 * 8);

    f32x4 oacc[2][2];
    #pragma unroll
    for (int rt = 0; rt < 2; ++rt)
        #pragma unroll
        for (int dt = 0; dt < 2; ++dt)
            oacc[rt][dt] = (f32x4){0.f, 0.f, 0.f, 0.f};
    float pden[2] = {0.f, 0.f};

    // depth-1 software pipeline over 12 K-tiles, fully unrolled
    Tile cur = load_tile(kh, vbase, zbh, mrow, wq0, l15, l4, 0);
    #pragma unroll
    for (int i = 0; i < 11; ++i) {
        Tile nxt = load_tile(kh, vbase, zbh, mrow, wq0, l15, l4, (i + 1) * 32);
        compute_tile(cur, qf, oacc, pden);
        cur = nxt;
    }
    compute_tile(cur, qf, oacc, pden);

    // denominator: sum over l4 groups (keys), replicated over l4
    #pragma unroll
    for (int rt = 0; rt < 2; ++rt) {
        pden[rt] += __shfl_xor(pden[rt], 16, 64);
        pden[rt] += __shfl_xor(pden[rt], 32, 64);
    }

    // epilogue: oacc row (l4*4+r) needs pden of that qrow (held at lane l4*4+r)
    #pragma unroll
    for (int rt = 0; rt < 2; ++rt) {
        #pragma unroll
        for (int r = 0; r < 4; ++r) {
            float den = __shfl(pden[rt], l4 * 4 + r, 64);
            float inv = 1.0f / den;
            int qrow = wq0 + rt * 16 + l4 * 4 + r;
            #pragma unroll
            for (int dt = 0; dt < 2; ++dt) {
                size_t off = (size_t)qrow * 32 + dt * 16 + l15;
                oh[off] = f2bf(oacc[rt][dt][r] * inv * bf2f(gh[off]));
            }
        }
    }
}

extern "C" void kernel_launch(void* const* d_in, const int* in_sizes, int n_in,
                              void* d_out, int out_size, void* d_ws, size_t ws_size,
                              hipStream_t stream) {
    (void)in_sizes; (void)n_in; (void)out_size; (void)ws_size;
    const float* m      = (const float*)d_in[0];
    const float* z      = (const float*)d_in[1];
    const float* mask   = (const float*)d_in[2];
    const float* ln_m_w = (const float*)d_in[3];
    const float* ln_m_b = (const float*)d_in[4];
    const float* ln_z_w = (const float*)d_in[5];
    const float* ln_z_b = (const float*)d_in[6];
    const float* w_z    = (const float*)d_in[7];
    const float* w_q    = (const float*)d_in[8];
    const float* w_k    = (const float*)d_in[9];
    const float* w_v    = (const float*)d_in[10];
    const float* w_g    = (const float*)d_in[11];
    const float* b_g    = (const float*)d_in[12];
    const float* w_o    = (const float*)d_in[13];
    const float* b_o    = (const float*)d_in[14];
    float* out = (float*)d_out;
    char* wsb = (char*)d_ws;

    const size_t NR = NRTOT;  // 49152 rows
    u16*   A   = (u16*)wsb;                      wsb += NR * 256 * 2;
    u16*   q   = (u16*)wsb;                      wsb += NR * 256 * 2;
    u16*   k   = (u16*)wsb;                      wsb += NR * 256 * 2;
    u16*   vT  = (u16*)wsb;                      wsb += NR * 256 * 2;
    u16*   o   = (u16*)wsb;                      wsb += NR * 256 * 2;
    u16*   g   = (u16*)wsb;                      wsb += NR * 256 * 2;
    float* zbp = (float*)wsb;                    wsb += (size_t)H * R * R * 4;
    u16*   Wt  = (u16*)wsb;                      wsb += (size_t)5 * 256 * 256 * 2;

    wprep_kernel<<<5 * 256, 256, 0, stream>>>(w_q, w_k, w_v, w_g, w_o, Wt);
    lnm_kernel<<<NR / 4, 256, 0, stream>>>(m, ln_m_w, ln_m_b, A);
    zbias_kernel<<<2304, 256, 0, stream>>>(z, ln_z_w, ln_z_b, w_z, zbp);
    qkvg_gemm<<<dim3(NR / 128, 4), 512, 0, stream>>>(A, Wt, b_g, q, k, vT, g);
    attn_kernel<<<dim3(H, S), 768, 0, stream>>>(q, k, vT, g, mask, zbp, o);
    out_gemm<<<NR / 128, 512, 0, stream>>>(o, Wt + (size_t)4 * 256 * 256, b_o, out);
}

// Round 17
// 299.201 us; speedup vs baseline: 1.1800x; 1.1800x over previous
//
#include <hip/hip_runtime.h>
#include <math.h>

#define S 128
#define R 384
#define CM 256
#define CZ 128
#define H 8
#define D 32
#define INFB 1e9f
#define LN_EPS 1e-5f
#define LOG2E 1.4426950408889634f

typedef unsigned short u16;
typedef short bf16x8 __attribute__((ext_vector_type(8)));
typedef short bf16x4 __attribute__((ext_vector_type(4)));
typedef float f32x4 __attribute__((ext_vector_type(4)));

#define NRTOT ((size_t)S * R)   // 49152 rows

__device__ inline float wave_reduce_sum(float v) {
    #pragma unroll
    for (int o = 32; o > 0; o >>= 1) v += __shfl_xor(v, o, 64);
    return v;
}

__device__ inline u16 f2bf(float f) {
    union { float f; unsigned int u; } x; x.f = f;
    unsigned int r = x.u + 0x7fffu + ((x.u >> 16) & 1u);
    return (u16)(r >> 16);
}

__device__ inline float bf2f(u16 v) {
    union { unsigned int u; float f; } x; x.u = ((unsigned int)v) << 16;
    return x.f;
}

// ---------------------------------------------------------------------------
// Weight prep: Wt[mi][n][k] = src_mi[k][n] as bf16; mi: 0=q(scaled),1=k,2=v,3=g,4=o
__global__ __launch_bounds__(256) void wprep_kernel(
    const float* __restrict__ wq, const float* __restrict__ wk,
    const float* __restrict__ wv, const float* __restrict__ wg,
    const float* __restrict__ wo, u16* __restrict__ Wt) {
    int n = blockIdx.x & 255;
    int mi = blockIdx.x >> 8;
    int kc = threadIdx.x;
    const float* src = mi == 0 ? wq : mi == 1 ? wk : mi == 2 ? wv
                     : mi == 3 ? wg : wo;
    float val = src[(size_t)kc * 256 + n];
    if (mi == 0) val *= 0.17677669529663687f * LOG2E;
    Wt[((size_t)mi * 256 + n) * 256 + kc] = f2bf(val);
}

// ---------------------------------------------------------------------------
// LN(m) -> A bf16 [S*R][256]. 4 rows per block, wave per row.
__global__ __launch_bounds__(256) void lnm_kernel(
    const float* __restrict__ m, const float* __restrict__ lnw,
    const float* __restrict__ lnb, u16* __restrict__ A) {
    int t = threadIdx.x;
    int wave = t >> 6, lane = t & 63;
    size_t row = (size_t)blockIdx.x * 4 + wave;
    float4 x = ((const float4*)(m + row * 256))[lane];
    float ss = wave_reduce_sum(x.x + x.y + x.z + x.w);
    float sq = wave_reduce_sum(x.x * x.x + x.y * x.y + x.z * x.z + x.w * x.w);
    float mu = ss * (1.0f / 256.0f);
    float var = sq * (1.0f / 256.0f) - mu * mu;
    float rstd = rsqrtf(var + LN_EPS);
    int c = lane * 4;
    ushort4 o4;
    o4.x = f2bf((x.x - mu) * rstd * lnw[c]     + lnb[c]);
    o4.y = f2bf((x.y - mu) * rstd * lnw[c + 1] + lnb[c + 1]);
    o4.z = f2bf((x.z - mu) * rstd * lnw[c + 2] + lnb[c + 2]);
    o4.w = f2bf((x.w - mu) * rstd * lnw[c + 3] + lnb[c + 3]);
    ((ushort4*)(A + row * 256))[lane] = o4;
}

// ---------------------------------------------------------------------------
// z_bias: algebra-folded, 16 lanes per (i,j) pair, 4 pairs per wave.
// TILED output: zbT[h][j/16][i][j%16] so attn reads dense 1KB bursts.
// Pre-scaled by LOG2E.
__global__ __launch_bounds__(256) void zbias_kernel(
    const float* __restrict__ z, const float* __restrict__ lnw,
    const float* __restrict__ lnb, const float* __restrict__ wz,
    float* __restrict__ zbias) {
    int t = threadIdx.x;
    int lane = t & 63, wave = t >> 6;
    int g = lane >> 4, u = lane & 15;
    int c0 = u * 8;

    float lw[8], lb[8];
    {
        float4 a = *(const float4*)(lnw + c0);
        float4 b = *(const float4*)(lnw + c0 + 4);
        lw[0]=a.x; lw[1]=a.y; lw[2]=a.z; lw[3]=a.w;
        lw[4]=b.x; lw[5]=b.y; lw[6]=b.z; lw[7]=b.w;
        float4 c = *(const float4*)(lnb + c0);
        float4 d = *(const float4*)(lnb + c0 + 4);
        lb[0]=c.x; lb[1]=c.y; lb[2]=c.z; lb[3]=c.w;
        lb[4]=d.x; lb[5]=d.y; lb[6]=d.z; lb[7]=d.w;
        #pragma unroll
        for (int i = 0; i < 8; ++i) { lw[i] *= LOG2E; lb[i] *= LOG2E; }
    }
    float uw[8][8];
    float bwp[8];
    #pragma unroll
    for (int h = 0; h < 8; ++h) bwp[h] = 0.f;
    #pragma unroll
    for (int i = 0; i < 8; ++i) {
        float4 w0 = *(const float4*)(wz + (size_t)(c0 + i) * 8);
        float4 w1 = *(const float4*)(wz + (size_t)(c0 + i) * 8 + 4);
        uw[i][0] = lw[i] * w0.x; uw[i][1] = lw[i] * w0.y;
        uw[i][2] = lw[i] * w0.z; uw[i][3] = lw[i] * w0.w;
        uw[i][4] = lw[i] * w1.x; uw[i][5] = lw[i] * w1.y;
        uw[i][6] = lw[i] * w1.z; uw[i][7] = lw[i] * w1.w;
        bwp[0] = fmaf(lb[i], w0.x, bwp[0]); bwp[1] = fmaf(lb[i], w0.y, bwp[1]);
        bwp[2] = fmaf(lb[i], w0.z, bwp[2]); bwp[3] = fmaf(lb[i], w0.w, bwp[3]);
        bwp[4] = fmaf(lb[i], w1.x, bwp[4]); bwp[5] = fmaf(lb[i], w1.y, bwp[5]);
        bwp[6] = fmaf(lb[i], w1.z, bwp[6]); bwp[7] = fmaf(lb[i], w1.w, bwp[7]);
    }

    const int nwaves = gridDim.x * 4;
    int wid = blockIdx.x * 4 + wave;
    #pragma unroll 1
    for (int it = 0; it < 4; ++it) {
        int p = (wid + it * nwaves) * 4 + g;
        const float* zp = z + (size_t)p * CZ + c0;
        float4 z0 = *(const float4*)zp;
        float4 z1 = *(const float4*)(zp + 4);
        float x[8] = {z0.x, z0.y, z0.z, z0.w, z1.x, z1.y, z1.z, z1.w};
        float ss = 0.f, sq = 0.f;
        #pragma unroll
        for (int i = 0; i < 8; ++i) { ss += x[i]; sq = fmaf(x[i], x[i], sq); }
        #pragma unroll
        for (int o = 1; o < 16; o <<= 1) {
            ss += __shfl_xor(ss, o, 64);
            sq += __shfl_xor(sq, o, 64);
        }
        float mu = ss * (1.0f / CZ);
        float var = sq * (1.0f / CZ) - mu * mu;
        float rstd = rsqrtf(var + LN_EPS);
        float ph[8];
        #pragma unroll
        for (int h = 0; h < 8; ++h) ph[h] = bwp[h];
        #pragma unroll
        for (int i = 0; i < 8; ++i) {
            float ti = (x[i] - mu) * rstd;
            #pragma unroll
            for (int h = 0; h < 8; ++h) ph[h] = fmaf(ti, uw[i][h], ph[h]);
        }
        #pragma unroll
        for (int h = 0; h < 8; ++h) {
            #pragma unroll
            for (int o = 1; o < 16; o <<= 1) ph[h] += __shfl_xor(ph[h], o, 64);
        }
        if (u < 8) {
            float outv = ph[0];
            if (u == 1) outv = ph[1];
            if (u == 2) outv = ph[2];
            if (u == 3) outv = ph[3];
            if (u == 4) outv = ph[4];
            if (u == 5) outv = ph[5];
            if (u == 6) outv = ph[6];
            if (u == 7) outv = ph[7];
            int i = p / R;           // q row
            int j = p - i * R;       // key
            // zbT[h][j/16][i][j%16]
            zbias[(((size_t)u * 24 + (j >> 4)) * R + i) * 16 + (j & 15)] = outv;
        }
    }
}

// ---------------------------------------------------------------------------
// qkvg GEMM: M=49152, K=256, one weight matrix per blockIdx.y.
// HEAD-MAJOR q,k,g: [h][S*R][32]. v written to TILED slot-permuted
// vTt[s][h][key32][dt][d%16][slot32] so attn's PV fragments are dense 1KB.
__global__ __launch_bounds__(512) void qkvg_gemm(
    const u16* __restrict__ A, const u16* __restrict__ Wt,
    const float* __restrict__ bg,
    u16* __restrict__ q, u16* __restrict__ k, u16* __restrict__ vT,
    u16* __restrict__ g) {
    int nb = blockIdx.y;
    size_t row0 = (size_t)blockIdx.x * 128;
    int t = threadIdx.x, lane = t & 63, wave = t >> 6;
    int l15 = lane & 15, l4 = lane >> 4;
    int wm = (wave >> 2) * 64, wn = (wave & 3) * 64;
    const u16* B = Wt + (size_t)nb * 256 * 256;
    const u16* Ab = A + (row0 + wm + l15) * 256 + l4 * 8;
    const u16* Bb = B + (size_t)(wn + l15) * 256 + l4 * 8;

    f32x4 acc[4][4];
    #pragma unroll
    for (int mt = 0; mt < 4; ++mt)
        #pragma unroll
        for (int nt = 0; nt < 4; ++nt)
            acc[mt][nt] = (f32x4){0.f, 0.f, 0.f, 0.f};

    #pragma unroll
    for (int kk = 0; kk < 8; ++kk) {
        bf16x8 af[4], bfr[4];
        #pragma unroll
        for (int mt = 0; mt < 4; ++mt)
            af[mt] = *(const bf16x8*)(Ab + (size_t)mt * 16 * 256 + kk * 32);
        #pragma unroll
        for (int nt = 0; nt < 4; ++nt)
            bfr[nt] = *(const bf16x8*)(Bb + (size_t)nt * 16 * 256 + kk * 32);
        #pragma unroll
        for (int mt = 0; mt < 4; ++mt)
            #pragma unroll
            for (int nt = 0; nt < 4; ++nt)
                acc[mt][nt] = __builtin_amdgcn_mfma_f32_16x16x32_bf16(
                    af[mt], bfr[nt], acc[mt][nt], 0, 0, 0);
    }

    if (nb == 3) {
        #pragma unroll
        for (int nt = 0; nt < 4; ++nt) {
            int col = wn + nt * 16 + l15;
            int hh = col >> 5, dd = col & 31;
            float bgv = bg[col];
            #pragma unroll
            for (int mt = 0; mt < 4; ++mt)
                #pragma unroll
                for (int r = 0; r < 4; ++r) {
                    size_t row = row0 + wm + mt * 16 + l4 * 4 + r;
                    g[((size_t)hh * NRTOT + row) * 32 + dd] =
                        f2bf(1.0f / (1.0f + __expf(-(acc[mt][nt][r] + bgv))));
                }
        }
    } else if (nb == 2) {
        #pragma unroll
        for (int nt = 0; nt < 4; ++nt) {
            int col = wn + nt * 16 + l15;
            int hh = col >> 5, dd = col & 31;
            int dt = dd >> 4, d15 = dd & 15;
            #pragma unroll
            for (int mt = 0; mt < 4; ++mt) {
                size_t row = row0 + wm + mt * 16 + l4 * 4;  // 4-aligned
                int ss = (int)(row / 384);
                int rr = (int)(row - (size_t)ss * 384);
                int kb = rr >> 5;
                int k5 = rr & 31;
                int slot = ((k5 & 15) >> 2) * 8 + ((k5 & 16) ? 4 : 0);  // k5&3==0
                ushort4 pk;
                pk.x = f2bf(acc[mt][nt][0]);
                pk.y = f2bf(acc[mt][nt][1]);
                pk.z = f2bf(acc[mt][nt][2]);
                pk.w = f2bf(acc[mt][nt][3]);
                size_t off = ((((size_t)(ss * 8 + hh) * 12 + kb) * 2 + dt) * 16
                              + d15) * 32 + slot;
                *(ushort4*)(vT + off) = pk;
            }
        }
    } else {
        u16* dst = nb == 0 ? q : k;
        #pragma unroll
        for (int nt = 0; nt < 4; ++nt) {
            int col = wn + nt * 16 + l15;
            int hh = col >> 5, dd = col & 31;
            #pragma unroll
            for (int mt = 0; mt < 4; ++mt)
                #pragma unroll
                for (int r = 0; r < 4; ++r) {
                    size_t row = row0 + wm + mt * 16 + l4 * 4 + r;
                    dst[((size_t)hh * NRTOT + row) * 32 + dd] = f2bf(acc[mt][nt][r]);
                }
        }
    }
}

// ---------------------------------------------------------------------------
// out GEMM: M=49152, N=256, K=256; A = o in HEAD-MAJOR [h][S*R][32].
__global__ __launch_bounds__(512) void out_gemm(
    const u16* __restrict__ A, const u16* __restrict__ Wt,
    const float* __restrict__ bo, float* __restrict__ out) {
    size_t row0 = (size_t)blockIdx.x * 128;
    int t = threadIdx.x, lane = t & 63, wave = t >> 6;
    int l15 = lane & 15, l4 = lane >> 4;
    int wm = (wave >> 2) * 64, wn = (wave & 3) * 64;
    const u16* Bb = Wt + (size_t)(wn + l15) * 256 + l4 * 8;

    f32x4 acc[4][4];
    #pragma unroll
    for (int mt = 0; mt < 4; ++mt)
        #pragma unroll
        for (int nt = 0; nt < 4; ++nt)
            acc[mt][nt] = (f32x4){0.f, 0.f, 0.f, 0.f};

    #pragma unroll
    for (int kk = 0; kk < 8; ++kk) {
        bf16x8 af[4], bfr[4];
        #pragma unroll
        for (int mt = 0; mt < 4; ++mt)
            af[mt] = *(const bf16x8*)(A +
                ((size_t)kk * NRTOT + row0 + wm + mt * 16 + l15) * 32 + l4 * 8);
        #pragma unroll
        for (int nt = 0; nt < 4; ++nt)
            bfr[nt] = *(const bf16x8*)(Bb + (size_t)nt * 16 * 256 + kk * 32);
        #pragma unroll
        for (int mt = 0; mt < 4; ++mt)
            #pragma unroll
            for (int nt = 0; nt < 4; ++nt)
                acc[mt][nt] = __builtin_amdgcn_mfma_f32_16x16x32_bf16(
                    af[mt], bfr[nt], acc[mt][nt], 0, 0, 0);
    }

    #pragma unroll
    for (int nt = 0; nt < 4; ++nt) {
        int col = wn + nt * 16 + l15;
        float bov = bo[col];
        #pragma unroll
        for (int mt = 0; mt < 4; ++mt)
            #pragma unroll
            for (int r = 0; r < 4; ++r) {
                size_t row = row0 + wm + mt * 16 + l4 * 4 + r;
                out[row * 256 + col] = acc[mt][nt][r] + bov;
            }
    }
}

// ---------------------------------------------------------------------------
// Attention v12: v10 structure (rolled loop, low VGPR) with fully DENSE
// loads: q/k head-major, vTt tiled fragments, zbT tiled bias — every load
// instruction covers a contiguous 1KB region. Zero LDS, zero barriers.
__global__ __launch_bounds__(768) void attn_kernel(
    const u16* __restrict__ q, const u16* __restrict__ k,
    const u16* __restrict__ vT, const u16* __restrict__ g,
    const float* __restrict__ mask, const float* __restrict__ zb,
    u16* __restrict__ o) {
    int h = blockIdx.x, s = blockIdx.y;
    int t = threadIdx.x;
    int lane = t & 63, wave = t >> 6;   // wave in [0,12)
    int l15 = lane & 15, l4 = lane >> 4;

    size_t hbase = ((size_t)h * NRTOT + (size_t)s * R) * 32;
    const u16* qh = q + hbase;
    const u16* kh = k + hbase;
    const u16* gh = g + hbase;
    u16* oh = o + hbase;
    const u16* vbase = vT + (size_t)(s * H + h) * 12 * 1024;  // [kb][dt][d15][32]
    const float* zbh = zb + (size_t)h * 24 * R * 16;          // [kb16][qrow][16]
    const float* mrow = mask + (size_t)s * R;
    const float MSC = INFB * LOG2E;

    int wq0 = wave * 32;
    bf16x8 qf[2];     // B-operand: col = qrow (l15), k-elems l4*8..
    #pragma unroll
    for (int rt = 0; rt < 2; ++rt)
        qf[rt] = *(const bf16x8*)(qh + (size_t)(wq0 + rt * 16 + l15) * 32 + l4 * 8);

    f32x4 oacc[2][2];
    #pragma unroll
    for (int rt = 0; rt < 2; ++rt)
        #pragma unroll
        for (int dt = 0; dt < 2; ++dt)
            oacc[rt][dt] = (f32x4){0.f, 0.f, 0.f, 0.f};
    float pden[2] = {0.f, 0.f};

    for (int kt = 0; kt < R; kt += 32) {
        int kb = kt >> 5;
        // --- loads (ALL dense 1KB bursts now) ---
        bf16x8 kf0 = *(const bf16x8*)(kh + (size_t)(kt + l15) * 32 + l4 * 8);
        bf16x8 kf1 = *(const bf16x8*)(kh + (size_t)(kt + 16 + l15) * 32 + l4 * 8);
        bf16x8 vb0 = *(const bf16x8*)(vbase + ((size_t)kb * 2 + 0) * 512
                                      + l15 * 32 + l4 * 8);
        bf16x8 vb1 = *(const bf16x8*)(vbase + ((size_t)kb * 2 + 1) * 512
                                      + l15 * 32 + l4 * 8);
        float4 mk0 = *(const float4*)(mrow + kt + l4 * 4);
        float4 mk1 = *(const float4*)(mrow + kt + 16 + l4 * 4);
        f32x4 zv0[2], zv1[2];
        #pragma unroll
        for (int rt = 0; rt < 2; ++rt) {
            zv0[rt] = *(const f32x4*)(zbh +
                ((size_t)(2 * kb) * R + wq0 + rt * 16 + l15) * 16 + l4 * 4);
            zv1[rt] = *(const f32x4*)(zbh +
                ((size_t)(2 * kb + 1) * R + wq0 + rt * 16 + l15) * 16 + l4 * 4);
        }
        float ma0 = (mk0.x - 1.0f) * MSC, ma1 = (mk0.y - 1.0f) * MSC;
        float ma2 = (mk0.z - 1.0f) * MSC, ma3 = (mk0.w - 1.0f) * MSC;
        float mb0 = (mk1.x - 1.0f) * MSC, mb1 = (mk1.y - 1.0f) * MSC;
        float mb2 = (mk1.z - 1.0f) * MSC, mb3 = (mk1.w - 1.0f) * MSC;

        // --- QK^T swapped, two 16-key tiles: C col=l15=qrow, row=l4*4+r=key ---
        const f32x4 z4 = {0.f, 0.f, 0.f, 0.f};
        f32x4 sf0[2], sf1[2];
        #pragma unroll
        for (int rt = 0; rt < 2; ++rt) {
            sf0[rt] = __builtin_amdgcn_mfma_f32_16x16x32_bf16(kf0, qf[rt], z4, 0, 0, 0);
            sf1[rt] = __builtin_amdgcn_mfma_f32_16x16x32_bf16(kf1, qf[rt], z4, 0, 0, 0);
        }

        // --- exp2, pack full 8-slot P fragment, full-K PV ---
        #pragma unroll
        for (int rt = 0; rt < 2; ++rt) {
            float e0 = exp2f(sf0[rt][0] + ma0 + zv0[rt][0]);
            float e1 = exp2f(sf0[rt][1] + ma1 + zv0[rt][1]);
            float e2 = exp2f(sf0[rt][2] + ma2 + zv0[rt][2]);
            float e3 = exp2f(sf0[rt][3] + ma3 + zv0[rt][3]);
            float e4 = exp2f(sf1[rt][0] + mb0 + zv1[rt][0]);
            float e5 = exp2f(sf1[rt][1] + mb1 + zv1[rt][1]);
            float e6 = exp2f(sf1[rt][2] + mb2 + zv1[rt][2]);
            float e7 = exp2f(sf1[rt][3] + mb3 + zv1[rt][3]);
            pden[rt] += ((e0 + e1) + (e2 + e3)) + ((e4 + e5) + (e6 + e7));
            bf16x8 pa;
            pa[0] = (short)f2bf(e0); pa[1] = (short)f2bf(e1);
            pa[2] = (short)f2bf(e2); pa[3] = (short)f2bf(e3);
            pa[4] = (short)f2bf(e4); pa[5] = (short)f2bf(e5);
            pa[6] = (short)f2bf(e6); pa[7] = (short)f2bf(e7);
            oacc[rt][0] = __builtin_amdgcn_mfma_f32_16x16x32_bf16(
                pa, vb0, oacc[rt][0], 0, 0, 0);
            oacc[rt][1] = __builtin_amdgcn_mfma_f32_16x16x32_bf16(
                pa, vb1, oacc[rt][1], 0, 0, 0);
        }
    }

    // denominator: sum over l4 groups (keys), replicated over l4
    #pragma unroll
    for (int rt = 0; rt < 2; ++rt) {
        pden[rt] += __shfl_xor(pden[rt], 16, 64);
        pden[rt] += __shfl_xor(pden[rt], 32, 64);
    }

    // epilogue: oacc row (l4*4+r) needs pden of that qrow (held at lane l4*4+r)
    #pragma unroll
    for (int rt = 0; rt < 2; ++rt) {
        #pragma unroll
        for (int r = 0; r < 4; ++r) {
            float den = __shfl(pden[rt], l4 * 4 + r, 64);
            float inv = 1.0f / den;
            int qrow = wq0 + rt * 16 + l4 * 4 + r;
            #pragma unroll
            for (int dt = 0; dt < 2; ++dt) {
                size_t off = (size_t)qrow * 32 + dt * 16 + l15;
                oh[off] = f2bf(oacc[rt][dt][r] * inv * bf2f(gh[off]));
            }
        }
    }
}

extern "C" void kernel_launch(void* const* d_in, const int* in_sizes, int n_in,
                              void* d_out, int out_size, void* d_ws, size_t ws_size,
                              hipStream_t stream) {
    (void)in_sizes; (void)n_in; (void)out_size; (void)ws_size;
    const float* m      = (const float*)d_in[0];
    const float* z      = (const float*)d_in[1];
    const float* mask   = (const float*)d_in[2];
    const float* ln_m_w = (const float*)d_in[3];
    const float* ln_m_b = (const float*)d_in[4];
    const float* ln_z_w = (const float*)d_in[5];
    const float* ln_z_b = (const float*)d_in[6];
    const float* w_z    = (const float*)d_in[7];
    const float* w_q    = (const float*)d_in[8];
    const float* w_k    = (const float*)d_in[9];
    const float* w_v    = (const float*)d_in[10];
    const float* w_g    = (const float*)d_in[11];
    const float* b_g    = (const float*)d_in[12];
    const float* w_o    = (const float*)d_in[13];
    const float* b_o    = (const float*)d_in[14];
    float* out = (float*)d_out;
    char* wsb = (char*)d_ws;

    const size_t NR = NRTOT;  // 49152 rows
    u16*   A   = (u16*)wsb;                      wsb += NR * 256 * 2;
    u16*   q   = (u16*)wsb;                      wsb += NR * 256 * 2;
    u16*   k   = (u16*)wsb;                      wsb += NR * 256 * 2;
    u16*   vT  = (u16*)wsb;                      wsb += NR * 256 * 2;
    u16*   o   = (u16*)wsb;                      wsb += NR * 256 * 2;
    u16*   g   = (u16*)wsb;                      wsb += NR * 256 * 2;
    float* zbp = (float*)wsb;                    wsb += (size_t)H * R * R * 4;
    u16*   Wt  = (u16*)wsb;                      wsb += (size_t)5 * 256 * 256 * 2;

    wprep_kernel<<<5 * 256, 256, 0, stream>>>(w_q, w_k, w_v, w_g, w_o, Wt);
    lnm_kernel<<<NR / 4, 256, 0, stream>>>(m, ln_m_w, ln_m_b, A);
    zbias_kernel<<<2304, 256, 0, stream>>>(z, ln_z_w, ln_z_b, w_z, zbp);
    qkvg_gemm<<<dim3(NR / 128, 4), 512, 0, stream>>>(A, Wt, b_g, q, k, vT, g);
    attn_kernel<<<dim3(H, S), 768, 0, stream>>>(q, k, vT, g, mask, zbp, o);
    out_gemm<<<NR / 128, 512, 0, stream>>>(o, Wt + (size_t)4 * 256 * 256, b_o, out);
}

// Round 18
// 256.672 us; speedup vs baseline: 1.3755x; 1.1657x over previous
//
#include <hip/hip_runtime.h>
#include <math.h>

#define S 128
#define R 384
#define CM 256
#define CZ 128
#define H 8
#define D 32
#define INFB 1e9f
#define LN_EPS 1e-5f
#define LOG2E 1.4426950408889634f

typedef unsigned short u16;
typedef short bf16x8 __attribute__((ext_vector_type(8)));
typedef short bf16x4 __attribute__((ext_vector_type(4)));
typedef float f32x4 __attribute__((ext_vector_type(4)));

#define NRTOT ((size_t)S * R)   // 49152 rows

__device__ inline float wave_reduce_sum(float v) {
    #pragma unroll
    for (int o = 32; o > 0; o >>= 1) v += __shfl_xor(v, o, 64);
    return v;
}

__device__ inline u16 f2bf(float f) {
    union { float f; unsigned int u; } x; x.f = f;
    unsigned int r = x.u + 0x7fffu + ((x.u >> 16) & 1u);
    return (u16)(r >> 16);
}

__device__ inline float bf2f(u16 v) {
    union { unsigned int u; float f; } x; x.u = ((unsigned int)v) << 16;
    return x.f;
}

// ---------------------------------------------------------------------------
// Weight prep -> TILED Wt[mi][n/16][kk][n%16][32] (dense 1KB GEMM B-frags).
// mi: 0=q(scaled),1=k,2=v,3=g,4=o
__global__ __launch_bounds__(256) void wprep_kernel(
    const float* __restrict__ wq, const float* __restrict__ wk,
    const float* __restrict__ wv, const float* __restrict__ wg,
    const float* __restrict__ wo, u16* __restrict__ Wt) {
    int n = blockIdx.x & 255;
    int mi = blockIdx.x >> 8;
    int kc = threadIdx.x;
    const float* src = mi == 0 ? wq : mi == 1 ? wk : mi == 2 ? wv
                     : mi == 3 ? wg : wo;
    float val = src[(size_t)kc * 256 + n];
    if (mi == 0) val *= 0.17677669529663687f * LOG2E;
    size_t dst = (size_t)mi * 65536 + (size_t)(n >> 4) * 4096
               + (size_t)(kc >> 5) * 512 + (n & 15) * 32 + (kc & 31);
    Wt[dst] = f2bf(val);
}

// ---------------------------------------------------------------------------
// LN(m) -> TILED At[row/16][kk][row%16][32] bf16. 4 rows per block.
__global__ __launch_bounds__(256) void lnm_kernel(
    const float* __restrict__ m, const float* __restrict__ lnw,
    const float* __restrict__ lnb, u16* __restrict__ A) {
    int t = threadIdx.x;
    int wave = t >> 6, lane = t & 63;
    size_t row = (size_t)blockIdx.x * 4 + wave;
    float4 x = ((const float4*)(m + row * 256))[lane];
    float ss = wave_reduce_sum(x.x + x.y + x.z + x.w);
    float sq = wave_reduce_sum(x.x * x.x + x.y * x.y + x.z * x.z + x.w * x.w);
    float mu = ss * (1.0f / 256.0f);
    float var = sq * (1.0f / 256.0f) - mu * mu;
    float rstd = rsqrtf(var + LN_EPS);
    int c = lane * 4;
    ushort4 o4;
    o4.x = f2bf((x.x - mu) * rstd * lnw[c]     + lnb[c]);
    o4.y = f2bf((x.y - mu) * rstd * lnw[c + 1] + lnb[c + 1]);
    o4.z = f2bf((x.z - mu) * rstd * lnw[c + 2] + lnb[c + 2]);
    o4.w = f2bf((x.w - mu) * rstd * lnw[c + 3] + lnb[c + 3]);
    size_t dst = (row >> 4) * 4096 + (size_t)(lane >> 3) * 512
               + (row & 15) * 32 + (lane & 7) * 4;
    *(ushort4*)(A + dst) = o4;
}

// ---------------------------------------------------------------------------
// z_bias: TILED zbT[h][j/16][i][j%16]; pre-scaled by LOG2E.
__global__ __launch_bounds__(256) void zbias_kernel(
    const float* __restrict__ z, const float* __restrict__ lnw,
    const float* __restrict__ lnb, const float* __restrict__ wz,
    float* __restrict__ zbias) {
    int t = threadIdx.x;
    int lane = t & 63, wave = t >> 6;
    int g = lane >> 4, u = lane & 15;
    int c0 = u * 8;

    float lw[8], lb[8];
    {
        float4 a = *(const float4*)(lnw + c0);
        float4 b = *(const float4*)(lnw + c0 + 4);
        lw[0]=a.x; lw[1]=a.y; lw[2]=a.z; lw[3]=a.w;
        lw[4]=b.x; lw[5]=b.y; lw[6]=b.z; lw[7]=b.w;
        float4 c = *(const float4*)(lnb + c0);
        float4 d = *(const float4*)(lnb + c0 + 4);
        lb[0]=c.x; lb[1]=c.y; lb[2]=c.z; lb[3]=c.w;
        lb[4]=d.x; lb[5]=d.y; lb[6]=d.z; lb[7]=d.w;
        #pragma unroll
        for (int i = 0; i < 8; ++i) { lw[i] *= LOG2E; lb[i] *= LOG2E; }
    }
    float uw[8][8];
    float bwp[8];
    #pragma unroll
    for (int h = 0; h < 8; ++h) bwp[h] = 0.f;
    #pragma unroll
    for (int i = 0; i < 8; ++i) {
        float4 w0 = *(const float4*)(wz + (size_t)(c0 + i) * 8);
        float4 w1 = *(const float4*)(wz + (size_t)(c0 + i) * 8 + 4);
        uw[i][0] = lw[i] * w0.x; uw[i][1] = lw[i] * w0.y;
        uw[i][2] = lw[i] * w0.z; uw[i][3] = lw[i] * w0.w;
        uw[i][4] = lw[i] * w1.x; uw[i][5] = lw[i] * w1.y;
        uw[i][6] = lw[i] * w1.z; uw[i][7] = lw[i] * w1.w;
        bwp[0] = fmaf(lb[i], w0.x, bwp[0]); bwp[1] = fmaf(lb[i], w0.y, bwp[1]);
        bwp[2] = fmaf(lb[i], w0.z, bwp[2]); bwp[3] = fmaf(lb[i], w0.w, bwp[3]);
        bwp[4] = fmaf(lb[i], w1.x, bwp[4]); bwp[5] = fmaf(lb[i], w1.y, bwp[5]);
        bwp[6] = fmaf(lb[i], w1.z, bwp[6]); bwp[7] = fmaf(lb[i], w1.w, bwp[7]);
    }

    const int nwaves = gridDim.x * 4;
    int wid = blockIdx.x * 4 + wave;
    #pragma unroll 1
    for (int it = 0; it < 4; ++it) {
        int p = (wid + it * nwaves) * 4 + g;
        const float* zp = z + (size_t)p * CZ + c0;
        float4 z0 = *(const float4*)zp;
        float4 z1 = *(const float4*)(zp + 4);
        float x[8] = {z0.x, z0.y, z0.z, z0.w, z1.x, z1.y, z1.z, z1.w};
        float ss = 0.f, sq = 0.f;
        #pragma unroll
        for (int i = 0; i < 8; ++i) { ss += x[i]; sq = fmaf(x[i], x[i], sq); }
        #pragma unroll
        for (int o = 1; o < 16; o <<= 1) {
            ss += __shfl_xor(ss, o, 64);
            sq += __shfl_xor(sq, o, 64);
        }
        float mu = ss * (1.0f / CZ);
        float var = sq * (1.0f / CZ) - mu * mu;
        float rstd = rsqrtf(var + LN_EPS);
        float ph[8];
        #pragma unroll
        for (int h = 0; h < 8; ++h) ph[h] = bwp[h];
        #pragma unroll
        for (int i = 0; i < 8; ++i) {
            float ti = (x[i] - mu) * rstd;
            #pragma unroll
            for (int h = 0; h < 8; ++h) ph[h] = fmaf(ti, uw[i][h], ph[h]);
        }
        #pragma unroll
        for (int h = 0; h < 8; ++h) {
            #pragma unroll
            for (int o = 1; o < 16; o <<= 1) ph[h] += __shfl_xor(ph[h], o, 64);
        }
        if (u < 8) {
            float outv = ph[0];
            if (u == 1) outv = ph[1];
            if (u == 2) outv = ph[2];
            if (u == 3) outv = ph[3];
            if (u == 4) outv = ph[4];
            if (u == 5) outv = ph[5];
            if (u == 6) outv = ph[6];
            if (u == 7) outv = ph[7];
            int i = p / R;           // q row
            int j = p - i * R;       // key
            zbias[(((size_t)u * 24 + (j >> 4)) * R + i) * 16 + (j & 15)] = outv;
        }
    }
}

// ---------------------------------------------------------------------------
// qkvg GEMM: TILED At / Wt reads (dense 1KB frags). HEAD-MAJOR q,k,g;
// v -> TILED slot-permuted vTt[s][h][key32][dt][d%16][slot32].
__global__ __launch_bounds__(512) void qkvg_gemm(
    const u16* __restrict__ A, const u16* __restrict__ Wt,
    const float* __restrict__ bg,
    u16* __restrict__ q, u16* __restrict__ k, u16* __restrict__ vT,
    u16* __restrict__ g) {
    int nb = blockIdx.y;
    size_t row0 = (size_t)blockIdx.x * 128;
    int t = threadIdx.x, lane = t & 63, wave = t >> 6;
    int l15 = lane & 15, l4 = lane >> 4;
    int wm = (wave >> 2) * 64, wn = (wave & 3) * 64;
    const u16* B = Wt + (size_t)nb * 65536;
    size_t arb = (row0 + wm) >> 4;   // A row-block base
    int nblk = wn >> 4;
    int lelem = l15 * 32 + l4 * 8;

    f32x4 acc[4][4];
    #pragma unroll
    for (int mt = 0; mt < 4; ++mt)
        #pragma unroll
        for (int nt = 0; nt < 4; ++nt)
            acc[mt][nt] = (f32x4){0.f, 0.f, 0.f, 0.f};

    #pragma unroll
    for (int kk = 0; kk < 8; ++kk) {
        bf16x8 af[4], bfr[4];
        #pragma unroll
        for (int mt = 0; mt < 4; ++mt)
            af[mt] = *(const bf16x8*)(A + ((arb + mt) * 8 + kk) * 512 + lelem);
        #pragma unroll
        for (int nt = 0; nt < 4; ++nt)
            bfr[nt] = *(const bf16x8*)(B + ((size_t)(nblk + nt) * 8 + kk) * 512 + lelem);
        #pragma unroll
        for (int mt = 0; mt < 4; ++mt)
            #pragma unroll
            for (int nt = 0; nt < 4; ++nt)
                acc[mt][nt] = __builtin_amdgcn_mfma_f32_16x16x32_bf16(
                    af[mt], bfr[nt], acc[mt][nt], 0, 0, 0);
    }

    if (nb == 3) {
        #pragma unroll
        for (int nt = 0; nt < 4; ++nt) {
            int col = wn + nt * 16 + l15;
            int hh = col >> 5, dd = col & 31;
            float bgv = bg[col];
            #pragma unroll
            for (int mt = 0; mt < 4; ++mt)
                #pragma unroll
                for (int r = 0; r < 4; ++r) {
                    size_t row = row0 + wm + mt * 16 + l4 * 4 + r;
                    g[((size_t)hh * NRTOT + row) * 32 + dd] =
                        f2bf(1.0f / (1.0f + __expf(-(acc[mt][nt][r] + bgv))));
                }
        }
    } else if (nb == 2) {
        #pragma unroll
        for (int nt = 0; nt < 4; ++nt) {
            int col = wn + nt * 16 + l15;
            int hh = col >> 5, dd = col & 31;
            int dt = dd >> 4, d15 = dd & 15;
            #pragma unroll
            for (int mt = 0; mt < 4; ++mt) {
                size_t row = row0 + wm + mt * 16 + l4 * 4;  // 4-aligned
                int ss = (int)(row / 384);
                int rr = (int)(row - (size_t)ss * 384);
                int kb = rr >> 5;
                int k5 = rr & 31;
                int slot = ((k5 & 15) >> 2) * 8 + ((k5 & 16) ? 4 : 0);
                ushort4 pk;
                pk.x = f2bf(acc[mt][nt][0]);
                pk.y = f2bf(acc[mt][nt][1]);
                pk.z = f2bf(acc[mt][nt][2]);
                pk.w = f2bf(acc[mt][nt][3]);
                size_t off = ((((size_t)(ss * 8 + hh) * 12 + kb) * 2 + dt) * 16
                              + d15) * 32 + slot;
                *(ushort4*)(vT + off) = pk;
            }
        }
    } else {
        u16* dst = nb == 0 ? q : k;
        #pragma unroll
        for (int nt = 0; nt < 4; ++nt) {
            int col = wn + nt * 16 + l15;
            int hh = col >> 5, dd = col & 31;
            #pragma unroll
            for (int mt = 0; mt < 4; ++mt)
                #pragma unroll
                for (int r = 0; r < 4; ++r) {
                    size_t row = row0 + wm + mt * 16 + l4 * 4 + r;
                    dst[((size_t)hh * NRTOT + row) * 32 + dd] = f2bf(acc[mt][nt][r]);
                }
        }
    }
}

// ---------------------------------------------------------------------------
// out GEMM: A = o HEAD-MAJOR [h][S*R][32] (dense); B = TILED Wt[4].
__global__ __launch_bounds__(512) void out_gemm(
    const u16* __restrict__ A, const u16* __restrict__ Wt,
    const float* __restrict__ bo, float* __restrict__ out) {
    size_t row0 = (size_t)blockIdx.x * 128;
    int t = threadIdx.x, lane = t & 63, wave = t >> 6;
    int l15 = lane & 15, l4 = lane >> 4;
    int wm = (wave >> 2) * 64, wn = (wave & 3) * 64;
    int nblk = wn >> 4;
    int lelem = l15 * 32 + l4 * 8;

    f32x4 acc[4][4];
    #pragma unroll
    for (int mt = 0; mt < 4; ++mt)
        #pragma unroll
        for (int nt = 0; nt < 4; ++nt)
            acc[mt][nt] = (f32x4){0.f, 0.f, 0.f, 0.f};

    #pragma unroll
    for (int kk = 0; kk < 8; ++kk) {
        bf16x8 af[4], bfr[4];
        #pragma unroll
        for (int mt = 0; mt < 4; ++mt)
            af[mt] = *(const bf16x8*)(A +
                ((size_t)kk * NRTOT + row0 + wm + mt * 16 + l15) * 32 + l4 * 8);
        #pragma unroll
        for (int nt = 0; nt < 4; ++nt)
            bfr[nt] = *(const bf16x8*)(Wt + ((size_t)(nblk + nt) * 8 + kk) * 512 + lelem);
        #pragma unroll
        for (int mt = 0; mt < 4; ++mt)
            #pragma unroll
            for (int nt = 0; nt < 4; ++nt)
                acc[mt][nt] = __builtin_amdgcn_mfma_f32_16x16x32_bf16(
                    af[mt], bfr[nt], acc[mt][nt], 0, 0, 0);
    }

    #pragma unroll
    for (int nt = 0; nt < 4; ++nt) {
        int col = wn + nt * 16 + l15;
        float bov = bo[col];
        #pragma unroll
        for (int mt = 0; mt < 4; ++mt)
            #pragma unroll
            for (int r = 0; r < 4; ++r) {
                size_t row = row0 + wm + mt * 16 + l4 * 4 + r;
                out[row * 256 + col] = acc[mt][nt][r] + bov;
            }
    }
}

// ---------------------------------------------------------------------------
// Attention v12 (unchanged from round 17): fully dense loads, zero LDS,
// zero barriers, swapped QK^T, full-K=32 slot-permuted PV.
__global__ __launch_bounds__(768) void attn_kernel(
    const u16* __restrict__ q, const u16* __restrict__ k,
    const u16* __restrict__ vT, const u16* __restrict__ g,
    const float* __restrict__ mask, const float* __restrict__ zb,
    u16* __restrict__ o) {
    int h = blockIdx.x, s = blockIdx.y;
    int t = threadIdx.x;
    int lane = t & 63, wave = t >> 6;   // wave in [0,12)
    int l15 = lane & 15, l4 = lane >> 4;

    size_t hbase = ((size_t)h * NRTOT + (size_t)s * R) * 32;
    const u16* qh = q + hbase;
    const u16* kh = k + hbase;
    const u16* gh = g + hbase;
    u16* oh = o + hbase;
    const u16* vbase = vT + (size_t)(s * H + h) * 12 * 1024;
    const float* zbh = zb + (size_t)h * 24 * R * 16;
    const float* mrow = mask + (size_t)s * R;
    const float MSC = INFB * LOG2E;

    int wq0 = wave * 32;
    bf16x8 qf[2];
    #pragma unroll
    for (int rt = 0; rt < 2; ++rt)
        qf[rt] = *(const bf16x8*)(qh + (size_t)(wq0 + rt * 16 + l15) * 32 + l4 * 8);

    f32x4 oacc[2][2];
    #pragma unroll
    for (int rt = 0; rt < 2; ++rt)
        #pragma unroll
        for (int dt = 0; dt < 2; ++dt)
            oacc[rt][dt] = (f32x4){0.f, 0.f, 0.f, 0.f};
    float pden[2] = {0.f, 0.f};

    for (int kt = 0; kt < R; kt += 32) {
        int kb = kt >> 5;
        bf16x8 kf0 = *(const bf16x8*)(kh + (size_t)(kt + l15) * 32 + l4 * 8);
        bf16x8 kf1 = *(const bf16x8*)(kh + (size_t)(kt + 16 + l15) * 32 + l4 * 8);
        bf16x8 vb0 = *(const bf16x8*)(vbase + ((size_t)kb * 2 + 0) * 512
                                      + l15 * 32 + l4 * 8);
        bf16x8 vb1 = *(const bf16x8*)(vbase + ((size_t)kb * 2 + 1) * 512
                                      + l15 * 32 + l4 * 8);
        float4 mk0 = *(const float4*)(mrow + kt + l4 * 4);
        float4 mk1 = *(const float4*)(mrow + kt + 16 + l4 * 4);
        f32x4 zv0[2], zv1[2];
        #pragma unroll
        for (int rt = 0; rt < 2; ++rt) {
            zv0[rt] = *(const f32x4*)(zbh +
                ((size_t)(2 * kb) * R + wq0 + rt * 16 + l15) * 16 + l4 * 4);
            zv1[rt] = *(const f32x4*)(zbh +
                ((size_t)(2 * kb + 1) * R + wq0 + rt * 16 + l15) * 16 + l4 * 4);
        }
        float ma0 = (mk0.x - 1.0f) * MSC, ma1 = (mk0.y - 1.0f) * MSC;
        float ma2 = (mk0.z - 1.0f) * MSC, ma3 = (mk0.w - 1.0f) * MSC;
        float mb0 = (mk1.x - 1.0f) * MSC, mb1 = (mk1.y - 1.0f) * MSC;
        float mb2 = (mk1.z - 1.0f) * MSC, mb3 = (mk1.w - 1.0f) * MSC;

        const f32x4 z4 = {0.f, 0.f, 0.f, 0.f};
        f32x4 sf0[2], sf1[2];
        #pragma unroll
        for (int rt = 0; rt < 2; ++rt) {
            sf0[rt] = __builtin_amdgcn_mfma_f32_16x16x32_bf16(kf0, qf[rt], z4, 0, 0, 0);
            sf1[rt] = __builtin_amdgcn_mfma_f32_16x16x32_bf16(kf1, qf[rt], z4, 0, 0, 0);
        }

        #pragma unroll
        for (int rt = 0; rt < 2; ++rt) {
            float e0 = exp2f(sf0[rt][0] + ma0 + zv0[rt][0]);
            float e1 = exp2f(sf0[rt][1] + ma1 + zv0[rt][1]);
            float e2 = exp2f(sf0[rt][2] + ma2 + zv0[rt][2]);
            float e3 = exp2f(sf0[rt][3] + ma3 + zv0[rt][3]);
            float e4 = exp2f(sf1[rt][0] + mb0 + zv1[rt][0]);
            float e5 = exp2f(sf1[rt][1] + mb1 + zv1[rt][1]);
            float e6 = exp2f(sf1[rt][2] + mb2 + zv1[rt][2]);
            float e7 = exp2f(sf1[rt][3] + mb3 + zv1[rt][3]);
            pden[rt] += ((e0 + e1) + (e2 + e3)) + ((e4 + e5) + (e6 + e7));
            bf16x8 pa;
            pa[0] = (short)f2bf(e0); pa[1] = (short)f2bf(e1);
            pa[2] = (short)f2bf(e2); pa[3] = (short)f2bf(e3);
            pa[4] = (short)f2bf(e4); pa[5] = (short)f2bf(e5);
            pa[6] = (short)f2bf(e6); pa[7] = (short)f2bf(e7);
            oacc[rt][0] = __builtin_amdgcn_mfma_f32_16x16x32_bf16(
                pa, vb0, oacc[rt][0], 0, 0, 0);
            oacc[rt][1] = __builtin_amdgcn_mfma_f32_16x16x32_bf16(
                pa, vb1, oacc[rt][1], 0, 0, 0);
        }
    }

    #pragma unroll
    for (int rt = 0; rt < 2; ++rt) {
        pden[rt] += __shfl_xor(pden[rt], 16, 64);
        pden[rt] += __shfl_xor(pden[rt], 32, 64);
    }

    #pragma unroll
    for (int rt = 0; rt < 2; ++rt) {
        #pragma unroll
        for (int r = 0; r < 4; ++r) {
            float den = __shfl(pden[rt], l4 * 4 + r, 64);
            float inv = 1.0f / den;
            int qrow = wq0 + rt * 16 + l4 * 4 + r;
            #pragma unroll
            for (int dt = 0; dt < 2; ++dt) {
                size_t off = (size_t)qrow * 32 + dt * 16 + l15;
                oh[off] = f2bf(oacc[rt][dt][r] * inv * bf2f(gh[off]));
            }
        }
    }
}

extern "C" void kernel_launch(void* const* d_in, const int* in_sizes, int n_in,
                              void* d_out, int out_size, void* d_ws, size_t ws_size,
                              hipStream_t stream) {
    (void)in_sizes; (void)n_in; (void)out_size; (void)ws_size;
    const float* m      = (const float*)d_in[0];
    const float* z      = (const float*)d_in[1];
    const float* mask   = (const float*)d_in[2];
    const float* ln_m_w = (const float*)d_in[3];
    const float* ln_m_b = (const float*)d_in[4];
    const float* ln_z_w = (const float*)d_in[5];
    const float* ln_z_b = (const float*)d_in[6];
    const float* w_z    = (const float*)d_in[7];
    const float* w_q    = (const float*)d_in[8];
    const float* w_k    = (const float*)d_in[9];
    const float* w_v    = (const float*)d_in[10];
    const float* w_g    = (const float*)d_in[11];
    const float* b_g    = (const float*)d_in[12];
    const float* w_o    = (const float*)d_in[13];
    const float* b_o    = (const float*)d_in[14];
    float* out = (float*)d_out;
    char* wsb = (char*)d_ws;

    const size_t NR = NRTOT;  // 49152 rows
    u16*   A   = (u16*)wsb;                      wsb += NR * 256 * 2;
    u16*   q   = (u16*)wsb;                      wsb += NR * 256 * 2;
    u16*   k   = (u16*)wsb;                      wsb += NR * 256 * 2;
    u16*   vT  = (u16*)wsb;                      wsb += NR * 256 * 2;
    u16*   o   = (u16*)wsb;                      wsb += NR * 256 * 2;
    u16*   g   = (u16*)wsb;                      wsb += NR * 256 * 2;
    float* zbp = (float*)wsb;                    wsb += (size_t)H * R * R * 4;
    u16*   Wt  = (u16*)wsb;                      wsb += (size_t)5 * 256 * 256 * 2;

    wprep_kernel<<<5 * 256, 256, 0, stream>>>(w_q, w_k, w_v, w_g, w_o, Wt);
    lnm_kernel<<<NR / 4, 256, 0, stream>>>(m, ln_m_w, ln_m_b, A);
    zbias_kernel<<<2304, 256, 0, stream>>>(z, ln_z_w, ln_z_b, w_z, zbp);
    qkvg_gemm<<<dim3(NR / 128, 4), 512, 0, stream>>>(A, Wt, b_g, q, k, vT, g);
    attn_kernel<<<dim3(H, S), 768, 0, stream>>>(q, k, vT, g, mask, zbp, o);
    out_gemm<<<NR / 128, 512, 0, stream>>>(o, Wt + (size_t)4 * 65536, b_o, out);
}

// Round 19
// 255.041 us; speedup vs baseline: 1.3843x; 1.0064x over previous
//
#include <hip/hip_runtime.h>
#include <math.h>

#define S 128
#define R 384
#define CM 256
#define CZ 128
#define H 8
#define D 32
#define INFB 1e9f
#define LN_EPS 1e-5f
#define LOG2E 1.4426950408889634f

typedef unsigned short u16;
typedef short bf16x8 __attribute__((ext_vector_type(8)));
typedef short bf16x4 __attribute__((ext_vector_type(4)));
typedef float f32x4 __attribute__((ext_vector_type(4)));

#define NRTOT ((size_t)S * R)   // 49152 rows

__device__ inline float wave_reduce_sum(float v) {
    #pragma unroll
    for (int o = 32; o > 0; o >>= 1) v += __shfl_xor(v, o, 64);
    return v;
}

__device__ inline u16 f2bf(float f) {
    union { float f; unsigned int u; } x; x.f = f;
    unsigned int r = x.u + 0x7fffu + ((x.u >> 16) & 1u);
    return (u16)(r >> 16);
}

__device__ inline float bf2f(u16 v) {
    union { unsigned int u; float f; } x; x.u = ((unsigned int)v) << 16;
    return x.f;
}

// ---------------------------------------------------------------------------
// Weight prep -> TILED Wt[mi][n/16][kk][n%16][32] (dense 1KB GEMM B-frags).
// mi: 0=q(scaled),1=k,2=v,3=g,4=o
__global__ __launch_bounds__(256) void wprep_kernel(
    const float* __restrict__ wq, const float* __restrict__ wk,
    const float* __restrict__ wv, const float* __restrict__ wg,
    const float* __restrict__ wo, u16* __restrict__ Wt) {
    int n = blockIdx.x & 255;
    int mi = blockIdx.x >> 8;
    int kc = threadIdx.x;
    const float* src = mi == 0 ? wq : mi == 1 ? wk : mi == 2 ? wv
                     : mi == 3 ? wg : wo;
    float val = src[(size_t)kc * 256 + n];
    if (mi == 0) val *= 0.17677669529663687f * LOG2E;
    size_t dst = (size_t)mi * 65536 + (size_t)(n >> 4) * 4096
               + (size_t)(kc >> 5) * 512 + (n & 15) * 32 + (kc & 31);
    Wt[dst] = f2bf(val);
}

// ---------------------------------------------------------------------------
// LN(m) -> TILED At[row/16][kk][row%16][32] bf16. 4 rows per block.
__global__ __launch_bounds__(256) void lnm_kernel(
    const float* __restrict__ m, const float* __restrict__ lnw,
    const float* __restrict__ lnb, u16* __restrict__ A) {
    int t = threadIdx.x;
    int wave = t >> 6, lane = t & 63;
    size_t row = (size_t)blockIdx.x * 4 + wave;
    float4 x = ((const float4*)(m + row * 256))[lane];
    float ss = wave_reduce_sum(x.x + x.y + x.z + x.w);
    float sq = wave_reduce_sum(x.x * x.x + x.y * x.y + x.z * x.z + x.w * x.w);
    float mu = ss * (1.0f / 256.0f);
    float var = sq * (1.0f / 256.0f) - mu * mu;
    float rstd = rsqrtf(var + LN_EPS);
    int c = lane * 4;
    ushort4 o4;
    o4.x = f2bf((x.x - mu) * rstd * lnw[c]     + lnb[c]);
    o4.y = f2bf((x.y - mu) * rstd * lnw[c + 1] + lnb[c + 1]);
    o4.z = f2bf((x.z - mu) * rstd * lnw[c + 2] + lnb[c + 2]);
    o4.w = f2bf((x.w - mu) * rstd * lnw[c + 3] + lnb[c + 3]);
    size_t dst = (row >> 4) * 4096 + (size_t)(lane >> 3) * 512
               + (row & 15) * 32 + (lane & 7) * 4;
    *(ushort4*)(A + dst) = o4;
}

// ---------------------------------------------------------------------------
// z_bias: TILED zbT[h][j/16][i][j%16]; pre-scaled by LOG2E.
__global__ __launch_bounds__(256) void zbias_kernel(
    const float* __restrict__ z, const float* __restrict__ lnw,
    const float* __restrict__ lnb, const float* __restrict__ wz,
    float* __restrict__ zbias) {
    int t = threadIdx.x;
    int lane = t & 63, wave = t >> 6;
    int g = lane >> 4, u = lane & 15;
    int c0 = u * 8;

    float lw[8], lb[8];
    {
        float4 a = *(const float4*)(lnw + c0);
        float4 b = *(const float4*)(lnw + c0 + 4);
        lw[0]=a.x; lw[1]=a.y; lw[2]=a.z; lw[3]=a.w;
        lw[4]=b.x; lw[5]=b.y; lw[6]=b.z; lw[7]=b.w;
        float4 c = *(const float4*)(lnb + c0);
        float4 d = *(const float4*)(lnb + c0 + 4);
        lb[0]=c.x; lb[1]=c.y; lb[2]=c.z; lb[3]=c.w;
        lb[4]=d.x; lb[5]=d.y; lb[6]=d.z; lb[7]=d.w;
        #pragma unroll
        for (int i = 0; i < 8; ++i) { lw[i] *= LOG2E; lb[i] *= LOG2E; }
    }
    float uw[8][8];
    float bwp[8];
    #pragma unroll
    for (int h = 0; h < 8; ++h) bwp[h] = 0.f;
    #pragma unroll
    for (int i = 0; i < 8; ++i) {
        float4 w0 = *(const float4*)(wz + (size_t)(c0 + i) * 8);
        float4 w1 = *(const float4*)(wz + (size_t)(c0 + i) * 8 + 4);
        uw[i][0] = lw[i] * w0.x; uw[i][1] = lw[i] * w0.y;
        uw[i][2] = lw[i] * w0.z; uw[i][3] = lw[i] * w0.w;
        uw[i][4] = lw[i] * w1.x; uw[i][5] = lw[i] * w1.y;
        uw[i][6] = lw[i] * w1.z; uw[i][7] = lw[i] * w1.w;
        bwp[0] = fmaf(lb[i], w0.x, bwp[0]); bwp[1] = fmaf(lb[i], w0.y, bwp[1]);
        bwp[2] = fmaf(lb[i], w0.z, bwp[2]); bwp[3] = fmaf(lb[i], w0.w, bwp[3]);
        bwp[4] = fmaf(lb[i], w1.x, bwp[4]); bwp[5] = fmaf(lb[i], w1.y, bwp[5]);
        bwp[6] = fmaf(lb[i], w1.z, bwp[6]); bwp[7] = fmaf(lb[i], w1.w, bwp[7]);
    }

    const int nwaves = gridDim.x * 4;
    int wid = blockIdx.x * 4 + wave;
    #pragma unroll 1
    for (int it = 0; it < 4; ++it) {
        int p = (wid + it * nwaves) * 4 + g;
        const float* zp = z + (size_t)p * CZ + c0;
        float4 z0 = *(const float4*)zp;
        float4 z1 = *(const float4*)(zp + 4);
        float x[8] = {z0.x, z0.y, z0.z, z0.w, z1.x, z1.y, z1.z, z1.w};
        float ss = 0.f, sq = 0.f;
        #pragma unroll
        for (int i = 0; i < 8; ++i) { ss += x[i]; sq = fmaf(x[i], x[i], sq); }
        #pragma unroll
        for (int o = 1; o < 16; o <<= 1) {
            ss += __shfl_xor(ss, o, 64);
            sq += __shfl_xor(sq, o, 64);
        }
        float mu = ss * (1.0f / CZ);
        float var = sq * (1.0f / CZ) - mu * mu;
        float rstd = rsqrtf(var + LN_EPS);
        float ph[8];
        #pragma unroll
        for (int h = 0; h < 8; ++h) ph[h] = bwp[h];
        #pragma unroll
        for (int i = 0; i < 8; ++i) {
            float ti = (x[i] - mu) * rstd;
            #pragma unroll
            for (int h = 0; h < 8; ++h) ph[h] = fmaf(ti, uw[i][h], ph[h]);
        }
        #pragma unroll
        for (int h = 0; h < 8; ++h) {
            #pragma unroll
            for (int o = 1; o < 16; o <<= 1) ph[h] += __shfl_xor(ph[h], o, 64);
        }
        if (u < 8) {
            float outv = ph[0];
            if (u == 1) outv = ph[1];
            if (u == 2) outv = ph[2];
            if (u == 3) outv = ph[3];
            if (u == 4) outv = ph[4];
            if (u == 5) outv = ph[5];
            if (u == 6) outv = ph[6];
            if (u == 7) outv = ph[7];
            int i = p / R;           // q row
            int j = p - i * R;       // key
            zbias[(((size_t)u * 24 + (j >> 4)) * R + i) * 16 + (j & 15)] = outv;
        }
    }
}

// ---------------------------------------------------------------------------
// qkvg GEMM: TILED At / Wt reads (dense 1KB frags). HEAD-MAJOR q,k,g;
// v -> TILED slot-permuted vTt[s][h][key32][dt][d%16][slot32].
__global__ __launch_bounds__(512) void qkvg_gemm(
    const u16* __restrict__ A, const u16* __restrict__ Wt,
    const float* __restrict__ bg,
    u16* __restrict__ q, u16* __restrict__ k, u16* __restrict__ vT,
    u16* __restrict__ g) {
    int nb = blockIdx.y;
    size_t row0 = (size_t)blockIdx.x * 128;
    int t = threadIdx.x, lane = t & 63, wave = t >> 6;
    int l15 = lane & 15, l4 = lane >> 4;
    int wm = (wave >> 2) * 64, wn = (wave & 3) * 64;
    const u16* B = Wt + (size_t)nb * 65536;
    size_t arb = (row0 + wm) >> 4;   // A row-block base
    int nblk = wn >> 4;
    int lelem = l15 * 32 + l4 * 8;

    f32x4 acc[4][4];
    #pragma unroll
    for (int mt = 0; mt < 4; ++mt)
        #pragma unroll
        for (int nt = 0; nt < 4; ++nt)
            acc[mt][nt] = (f32x4){0.f, 0.f, 0.f, 0.f};

    #pragma unroll
    for (int kk = 0; kk < 8; ++kk) {
        bf16x8 af[4], bfr[4];
        #pragma unroll
        for (int mt = 0; mt < 4; ++mt)
            af[mt] = *(const bf16x8*)(A + ((arb + mt) * 8 + kk) * 512 + lelem);
        #pragma unroll
        for (int nt = 0; nt < 4; ++nt)
            bfr[nt] = *(const bf16x8*)(B + ((size_t)(nblk + nt) * 8 + kk) * 512 + lelem);
        #pragma unroll
        for (int mt = 0; mt < 4; ++mt)
            #pragma unroll
            for (int nt = 0; nt < 4; ++nt)
                acc[mt][nt] = __builtin_amdgcn_mfma_f32_16x16x32_bf16(
                    af[mt], bfr[nt], acc[mt][nt], 0, 0, 0);
    }

    if (nb == 3) {
        #pragma unroll
        for (int nt = 0; nt < 4; ++nt) {
            int col = wn + nt * 16 + l15;
            int hh = col >> 5, dd = col & 31;
            float bgv = bg[col];
            #pragma unroll
            for (int mt = 0; mt < 4; ++mt)
                #pragma unroll
                for (int r = 0; r < 4; ++r) {
                    size_t row = row0 + wm + mt * 16 + l4 * 4 + r;
                    g[((size_t)hh * NRTOT + row) * 32 + dd] =
                        f2bf(1.0f / (1.0f + __expf(-(acc[mt][nt][r] + bgv))));
                }
        }
    } else if (nb == 2) {
        #pragma unroll
        for (int nt = 0; nt < 4; ++nt) {
            int col = wn + nt * 16 + l15;
            int hh = col >> 5, dd = col & 31;
            int dt = dd >> 4, d15 = dd & 15;
            #pragma unroll
            for (int mt = 0; mt < 4; ++mt) {
                size_t row = row0 + wm + mt * 16 + l4 * 4;  // 4-aligned
                int ss = (int)(row / 384);
                int rr = (int)(row - (size_t)ss * 384);
                int kb = rr >> 5;
                int k5 = rr & 31;
                int slot = ((k5 & 15) >> 2) * 8 + ((k5 & 16) ? 4 : 0);
                ushort4 pk;
                pk.x = f2bf(acc[mt][nt][0]);
                pk.y = f2bf(acc[mt][nt][1]);
                pk.z = f2bf(acc[mt][nt][2]);
                pk.w = f2bf(acc[mt][nt][3]);
                size_t off = ((((size_t)(ss * 8 + hh) * 12 + kb) * 2 + dt) * 16
                              + d15) * 32 + slot;
                *(ushort4*)(vT + off) = pk;
            }
        }
    } else {
        u16* dst = nb == 0 ? q : k;
        #pragma unroll
        for (int nt = 0; nt < 4; ++nt) {
            int col = wn + nt * 16 + l15;
            int hh = col >> 5, dd = col & 31;
            #pragma unroll
            for (int mt = 0; mt < 4; ++mt)
                #pragma unroll
                for (int r = 0; r < 4; ++r) {
                    size_t row = row0 + wm + mt * 16 + l4 * 4 + r;
                    dst[((size_t)hh * NRTOT + row) * 32 + dd] = f2bf(acc[mt][nt][r]);
                }
        }
    }
}

// ---------------------------------------------------------------------------
// out GEMM: A = o HEAD-MAJOR [h][S*R][32] (dense); B = TILED Wt[4].
__global__ __launch_bounds__(512) void out_gemm(
    const u16* __restrict__ A, const u16* __restrict__ Wt,
    const float* __restrict__ bo, float* __restrict__ out) {
    size_t row0 = (size_t)blockIdx.x * 128;
    int t = threadIdx.x, lane = t & 63, wave = t >> 6;
    int l15 = lane & 15, l4 = lane >> 4;
    int wm = (wave >> 2) * 64, wn = (wave & 3) * 64;
    int nblk = wn >> 4;
    int lelem = l15 * 32 + l4 * 8;

    f32x4 acc[4][4];
    #pragma unroll
    for (int mt = 0; mt < 4; ++mt)
        #pragma unroll
        for (int nt = 0; nt < 4; ++nt)
            acc[mt][nt] = (f32x4){0.f, 0.f, 0.f, 0.f};

    #pragma unroll
    for (int kk = 0; kk < 8; ++kk) {
        bf16x8 af[4], bfr[4];
        #pragma unroll
        for (int mt = 0; mt < 4; ++mt)
            af[mt] = *(const bf16x8*)(A +
                ((size_t)kk * NRTOT + row0 + wm + mt * 16 + l15) * 32 + l4 * 8);
        #pragma unroll
        for (int nt = 0; nt < 4; ++nt)
            bfr[nt] = *(const bf16x8*)(Wt + ((size_t)(nblk + nt) * 8 + kk) * 512 + lelem);
        #pragma unroll
        for (int mt = 0; mt < 4; ++mt)
            #pragma unroll
            for (int nt = 0; nt < 4; ++nt)
                acc[mt][nt] = __builtin_amdgcn_mfma_f32_16x16x32_bf16(
                    af[mt], bfr[nt], acc[mt][nt], 0, 0, 0);
    }

    #pragma unroll
    for (int nt = 0; nt < 4; ++nt) {
        int col = wn + nt * 16 + l15;
        float bov = bo[col];
        #pragma unroll
        for (int mt = 0; mt < 4; ++mt)
            #pragma unroll
            for (int r = 0; r < 4; ++r) {
                size_t row = row0 + wm + mt * 16 + l4 * 4 + r;
                out[row * 256 + col] = acc[mt][nt][r] + bov;
            }
    }
}

// ---------------------------------------------------------------------------
// Attention v13: v12 + VALU diet. pden computed by MFMA with an all-ones
// B fragment (row-sums of the SAME bf16 P used for PV -> consistent
// normalization, zero cross-lane epilogue). P pack = 2-op round
// ((bits+0x8000)>>16) instead of 4-op RNE. Dense loads, no LDS/barriers.
__global__ __launch_bounds__(768) void attn_kernel(
    const u16* __restrict__ q, const u16* __restrict__ k,
    const u16* __restrict__ vT, const u16* __restrict__ g,
    const float* __restrict__ mask, const float* __restrict__ zb,
    u16* __restrict__ o) {
    int h = blockIdx.x, s = blockIdx.y;
    int t = threadIdx.x;
    int lane = t & 63, wave = t >> 6;   // wave in [0,12)
    int l15 = lane & 15, l4 = lane >> 4;

    size_t hbase = ((size_t)h * NRTOT + (size_t)s * R) * 32;
    const u16* qh = q + hbase;
    const u16* kh = k + hbase;
    const u16* gh = g + hbase;
    u16* oh = o + hbase;
    const u16* vbase = vT + (size_t)(s * H + h) * 12 * 1024;
    const float* zbh = zb + (size_t)h * 24 * R * 16;
    const float* mrow = mask + (size_t)s * R;
    const float MSC = INFB * LOG2E;

    int wq0 = wave * 32;
    bf16x8 qf[2];
    #pragma unroll
    for (int rt = 0; rt < 2; ++rt)
        qf[rt] = *(const bf16x8*)(qh + (size_t)(wq0 + rt * 16 + l15) * 32 + l4 * 8);

    bf16x8 ones;
    #pragma unroll
    for (int i = 0; i < 8; ++i) ones[i] = (short)0x3F80;  // bf16 1.0

    f32x4 oacc[2][2];
    f32x4 pdacc[2];
    #pragma unroll
    for (int rt = 0; rt < 2; ++rt) {
        pdacc[rt] = (f32x4){0.f, 0.f, 0.f, 0.f};
        #pragma unroll
        for (int dt = 0; dt < 2; ++dt)
            oacc[rt][dt] = (f32x4){0.f, 0.f, 0.f, 0.f};
    }

    for (int kt = 0; kt < R; kt += 32) {
        int kb = kt >> 5;
        bf16x8 kf0 = *(const bf16x8*)(kh + (size_t)(kt + l15) * 32 + l4 * 8);
        bf16x8 kf1 = *(const bf16x8*)(kh + (size_t)(kt + 16 + l15) * 32 + l4 * 8);
        bf16x8 vb0 = *(const bf16x8*)(vbase + ((size_t)kb * 2 + 0) * 512
                                      + l15 * 32 + l4 * 8);
        bf16x8 vb1 = *(const bf16x8*)(vbase + ((size_t)kb * 2 + 1) * 512
                                      + l15 * 32 + l4 * 8);
        float4 mk0 = *(const float4*)(mrow + kt + l4 * 4);
        float4 mk1 = *(const float4*)(mrow + kt + 16 + l4 * 4);
        f32x4 zv0[2], zv1[2];
        #pragma unroll
        for (int rt = 0; rt < 2; ++rt) {
            zv0[rt] = *(const f32x4*)(zbh +
                ((size_t)(2 * kb) * R + wq0 + rt * 16 + l15) * 16 + l4 * 4);
            zv1[rt] = *(const f32x4*)(zbh +
                ((size_t)(2 * kb + 1) * R + wq0 + rt * 16 + l15) * 16 + l4 * 4);
        }
        float ma0 = (mk0.x - 1.0f) * MSC, ma1 = (mk0.y - 1.0f) * MSC;
        float ma2 = (mk0.z - 1.0f) * MSC, ma3 = (mk0.w - 1.0f) * MSC;
        float mb0 = (mk1.x - 1.0f) * MSC, mb1 = (mk1.y - 1.0f) * MSC;
        float mb2 = (mk1.z - 1.0f) * MSC, mb3 = (mk1.w - 1.0f) * MSC;

        const f32x4 z4 = {0.f, 0.f, 0.f, 0.f};
        f32x4 sf0[2], sf1[2];
        #pragma unroll
        for (int rt = 0; rt < 2; ++rt) {
            sf0[rt] = __builtin_amdgcn_mfma_f32_16x16x32_bf16(kf0, qf[rt], z4, 0, 0, 0);
            sf1[rt] = __builtin_amdgcn_mfma_f32_16x16x32_bf16(kf1, qf[rt], z4, 0, 0, 0);
        }

        #pragma unroll
        for (int rt = 0; rt < 2; ++rt) {
            float e0 = exp2f(sf0[rt][0] + ma0 + zv0[rt][0]);
            float e1 = exp2f(sf0[rt][1] + ma1 + zv0[rt][1]);
            float e2 = exp2f(sf0[rt][2] + ma2 + zv0[rt][2]);
            float e3 = exp2f(sf0[rt][3] + ma3 + zv0[rt][3]);
            float e4 = exp2f(sf1[rt][0] + mb0 + zv1[rt][0]);
            float e5 = exp2f(sf1[rt][1] + mb1 + zv1[rt][1]);
            float e6 = exp2f(sf1[rt][2] + mb2 + zv1[rt][2]);
            float e7 = exp2f(sf1[rt][3] + mb3 + zv1[rt][3]);
            bf16x8 pa;
            pa[0] = (short)((__float_as_uint(e0) + 0x8000u) >> 16);
            pa[1] = (short)((__float_as_uint(e1) + 0x8000u) >> 16);
            pa[2] = (short)((__float_as_uint(e2) + 0x8000u) >> 16);
            pa[3] = (short)((__float_as_uint(e3) + 0x8000u) >> 16);
            pa[4] = (short)((__float_as_uint(e4) + 0x8000u) >> 16);
            pa[5] = (short)((__float_as_uint(e5) + 0x8000u) >> 16);
            pa[6] = (short)((__float_as_uint(e6) + 0x8000u) >> 16);
            pa[7] = (short)((__float_as_uint(e7) + 0x8000u) >> 16);
            oacc[rt][0] = __builtin_amdgcn_mfma_f32_16x16x32_bf16(
                pa, vb0, oacc[rt][0], 0, 0, 0);
            oacc[rt][1] = __builtin_amdgcn_mfma_f32_16x16x32_bf16(
                pa, vb1, oacc[rt][1], 0, 0, 0);
            pdacc[rt] = __builtin_amdgcn_mfma_f32_16x16x32_bf16(
                pa, ones, pdacc[rt], 0, 0, 0);
        }
    }

    // epilogue: pdacc[rt][r] is the denominator for qrow rt*16 + l4*4 + r
    // (same lane/row layout as oacc) — no cross-lane reduction needed.
    #pragma unroll
    for (int rt = 0; rt < 2; ++rt) {
        #pragma unroll
        for (int r = 0; r < 4; ++r) {
            float inv = 1.0f / pdacc[rt][r];
            int qrow = wq0 + rt * 16 + l4 * 4 + r;
            #pragma unroll
            for (int dt = 0; dt < 2; ++dt) {
                size_t off = (size_t)qrow * 32 + dt * 16 + l15;
                oh[off] = f2bf(oacc[rt][dt][r] * inv * bf2f(gh[off]));
            }
        }
    }
}

extern "C" void kernel_launch(void* const* d_in, const int* in_sizes, int n_in,
                              void* d_out, int out_size, void* d_ws, size_t ws_size,
                              hipStream_t stream) {
    (void)in_sizes; (void)n_in; (void)out_size; (void)ws_size;
    const float* m      = (const float*)d_in[0];
    const float* z      = (const float*)d_in[1];
    const float* mask   = (const float*)d_in[2];
    const float* ln_m_w = (const float*)d_in[3];
    const float* ln_m_b = (const float*)d_in[4];
    const float* ln_z_w = (const float*)d_in[5];
    const float* ln_z_b = (const float*)d_in[6];
    const float* w_z    = (const float*)d_in[7];
    const float* w_q    = (const float*)d_in[8];
    const float* w_k    = (const float*)d_in[9];
    const float* w_v    = (const float*)d_in[10];
    const float* w_g    = (const float*)d_in[11];
    const float* b_g    = (const float*)d_in[12];
    const float* w_o    = (const float*)d_in[13];
    const float* b_o    = (const float*)d_in[14];
    float* out = (float*)d_out;
    char* wsb = (char*)d_ws;

    const size_t NR = NRTOT;  // 49152 rows
    u16*   A   = (u16*)wsb;                      wsb += NR * 256 * 2;
    u16*   q   = (u16*)wsb;                      wsb += NR * 256 * 2;
    u16*   k   = (u16*)wsb;                      wsb += NR * 256 * 2;
    u16*   vT  = (u16*)wsb;                      wsb += NR * 256 * 2;
    u16*   o   = (u16*)wsb;                      wsb += NR * 256 * 2;
    u16*   g   = (u16*)wsb;                      wsb += NR * 256 * 2;
    float* zbp = (float*)wsb;                    wsb += (size_t)H * R * R * 4;
    u16*   Wt  = (u16*)wsb;                      wsb += (size_t)5 * 256 * 256 * 2;

    wprep_kernel<<<5 * 256, 256, 0, stream>>>(w_q, w_k, w_v, w_g, w_o, Wt);
    lnm_kernel<<<NR / 4, 256, 0, stream>>>(m, ln_m_w, ln_m_b, A);
    zbias_kernel<<<2304, 256, 0, stream>>>(z, ln_z_w, ln_z_b, w_z, zbp);
    qkvg_gemm<<<dim3(NR / 128, 4), 512, 0, stream>>>(A, Wt, b_g, q, k, vT, g);
    attn_kernel<<<dim3(H, S), 768, 0, stream>>>(q, k, vT, g, mask, zbp, o);
    out_gemm<<<NR / 128, 512, 0, stream>>>(o, Wt + (size_t)4 * 65536, b_o, out);
}